// Round 4
// baseline (2494.408 us; speedup 1.0000x reference)
//
#include <hip/hip_runtime.h>

#define N_PTS  16384
#define B_SZ   8
#define NGROUP 1024
#define KNN_K  32
#define ATTR   7

// d_out layout (floats), reference return order:
// neighborhood (8,1024,32,7), center_idx (8,1024), centroids_attrs (8,1024,7), centroids_coors (8,1024,3)
#define OFF_NB     0
#define OFF_IDX    (B_SZ * NGROUP * KNN_K * ATTR)            // 1835008
#define OFF_CATTR  (OFF_IDX + B_SZ * NGROUP)                 // 1843200
#define OFF_CCOORD (OFF_CATTR + B_SZ * NGROUP * ATTR)        // 1900544

typedef float v2f __attribute__((ext_vector_type(2)));                 // packed-f32 math
typedef float f2u __attribute__((ext_vector_type(2), aligned(4)));     // 4B-aligned vec load

// Forced VOP3P packed fp32 (gfx90a+/gfx950).
__device__ __forceinline__ v2f pk_add(v2f a, v2f b) {
    v2f d; asm("v_pk_add_f32 %0, %1, %2" : "=v"(d) : "v"(a), "v"(b)); return d;
}
__device__ __forceinline__ v2f pk_mul(v2f a, v2f b) {
    v2f d; asm("v_pk_mul_f32 %0, %1, %2" : "=v"(d) : "v"(a), "v"(b)); return d;
}

// ---------------------------------------------------------------------------
// Kernel 0: prep — x2[b][n] = sum_a xyz[b][n][a]^2 (sequential, no FMA) and
// SoA transpose xt[b][a][n] for coalesced KNN staging.
// ---------------------------------------------------------------------------
__global__ void prep_kernel(const float* __restrict__ xyz, float* __restrict__ x2,
                            float* __restrict__ xt) {
#pragma clang fp contract(off)
    int i = blockIdx.x * blockDim.x + threadIdx.x;
    if (i >= B_SZ * N_PTS) return;
    const int b = i >> 14;
    const int p = i & (N_PTS - 1);
    const float* q = xyz + (size_t)i * ATTR;
    f2u a01 = *(const f2u*)q;
    f2u a23 = *(const f2u*)(q + 2);
    f2u a45 = *(const f2u*)(q + 4);
    float a6 = q[6];
    float s = a01.x * a01.x;
    s = s + a01.y * a01.y;
    s = s + a23.x * a23.x;
    s = s + a23.y * a23.y;
    s = s + a45.x * a45.x;
    s = s + a45.y * a45.y;
    s = s + a6 * a6;
    x2[i] = s;
    float* T = xt + (size_t)b * ATTR * N_PTS + p;
    T[0 * N_PTS] = a01.x;
    T[1 * N_PTS] = a01.y;
    T[2 * N_PTS] = a23.x;
    T[3 * N_PTS] = a23.y;
    T[4 * N_PTS] = a45.x;
    T[5 * N_PTS] = a45.y;
    T[6 * N_PTS] = a6;
}

// ---------------------------------------------------------------------------
// Kernel 1: farthest point sampling. One 1024-thread block per batch.
// __launch_bounds__(1024, 4): exactly 1 block/CU -> 128 VGPR budget so the
// 64-float/thread point state lives in architectural VGPRs (R3's 48-VGPR
// allocation forced AGPR/spill traffic on every pk-asm operand).
// ---------------------------------------------------------------------------
__global__ __launch_bounds__(1024, 4) void fps_kernel(const float* __restrict__ xyz,
                                                      float* __restrict__ out) {
#pragma clang fp contract(off)
    const int b = blockIdx.x;
    const int t = threadIdx.x;
    const int lane = t & 63;
    const float* X = xyz + (size_t)b * N_PTS * ATTR;

    v2f px[8], py[8], pz[8], pd[8];
#pragma unroll
    for (int j = 0; j < 8; ++j) {
        const int p0 = t + (j << 11);              // t + (2j)*1024
        const float* q0 = X + (size_t)p0 * ATTR;
        const float* q1 = q0 + (size_t)1024 * ATTR;
        f2u u0 = *(const f2u*)q0; float z0 = q0[2];
        f2u u1 = *(const f2u*)q1; float z1 = q1[2];
        px[j] = (v2f){u0.x, u1.x};
        py[j] = (v2f){u0.y, u1.y};
        pz[j] = (v2f){z0, z1};
        pd[j] = (v2f){1e10f, 1e10f};
    }

    __shared__ unsigned long long slot[3];
    __shared__ int sel[NGROUP];
    if (t == 0) { slot[0] = 0ull; sel[0] = 0; }
    float cx = X[0], cy = X[1], cz = X[2];        // farthest=0 initial centroid
    __syncthreads();

    for (int s = 0; s < NGROUP - 1; ++s) {
        const v2f ncx = {-cx, -cx}, ncy = {-cy, -cy}, ncz = {-cz, -cz};
        v2f pm;
#pragma unroll
        for (int j = 0; j < 8; ++j) {
            v2f dx = pk_add(px[j], ncx);
            v2f dy = pk_add(py[j], ncy);
            v2f dz = pk_add(pz[j], ncz);
            v2f a  = pk_mul(dx, dx);
            a = pk_add(a, pk_mul(dy, dy));        // (dx^2+dy^2) — unfused
            a = pk_add(a, pk_mul(dz, dz));        // + dz^2 — sequential
            v2f nd;
            nd.x = fminf(pd[j].x, a.x);
            nd.y = fminf(pd[j].y, a.y);
            pd[j] = nd;
            if (j == 0) { pm = nd; }
            else { pm.x = fmaxf(pm.x, nd.x); pm.y = fmaxf(pm.y, nd.y); }
        }
        const float tmax = fmaxf(pm.x, pm.y);
        // f32 wave-max butterfly
        float wmax = tmax;
#pragma unroll
        for (int off = 1; off < 64; off <<= 1)
            wmax = fmaxf(wmax, __shfl_xor(wmax, off));
        // owner lanes resolve their smallest matching point index
        int myp = 0x7fffffff;
        if (tmax == wmax) {
#pragma unroll
            for (int j = 7; j >= 0; --j) {        // descending: final = lowest p
                if (pd[j].y == wmax) myp = t + ((2 * j + 1) << 10);
                if (pd[j].x == wmax) myp = t + ((2 * j) << 10);
            }
        }
        unsigned long long m = __ballot(tmax == wmax);
        int wp = __shfl(myp, __ffsll(m) - 1);
        if (__popcll(m) > 1) {                    // exact-tie path (rare), exact min-p
            unsigned long long mm = m;
            while (mm) {
                int l = __ffsll(mm) - 1; mm &= mm - 1;
                int pp = __shfl(myp, l);
                wp = min(wp, pp);
            }
        }
        // monotone key: larger d wins; tie -> smaller index. d >= 0 so float
        // bits are order-preserving as u32.
        if (lane == 0)
            atomicMax(&slot[s % 3],
                      ((unsigned long long)__float_as_uint(wmax) << 32) |
                      (unsigned)(N_PTS - wp));
        if (t == 0) slot[(s + 1) % 3] = 0ull;     // barrier-ordered reset
        __syncthreads();
        const unsigned long long key = slot[s % 3];
        int bidx = N_PTS - (int)(unsigned)key;
        bidx = __builtin_amdgcn_readfirstlane(bidx);
        if (t == 0) sel[s + 1] = bidx;
        // uniform (SGPR) address -> scalar load of winner coords, L2-hit.
        const float* q = X + (size_t)bidx * ATTR;
        cx = q[0]; cy = q[1]; cz = q[2];
    }
    __syncthreads();

    // outputs: center_idx, centroids_attrs, centroids_coors (1024 threads = 1024 groups)
    {
        const int g = t;
        const int idx = sel[g];
        const float* q = X + (size_t)idx * ATTR;
        float a0 = q[0], a1 = q[1], a2 = q[2], a3 = q[3], a4 = q[4], a5 = q[5], a6 = q[6];
        out[OFF_IDX + b * NGROUP + g] = (float)idx;
        float* ca = out + OFF_CATTR + (size_t)(b * NGROUP + g) * ATTR;
        ca[0] = a0; ca[1] = a1; ca[2] = a2; ca[3] = a3; ca[4] = a4; ca[5] = a5; ca[6] = a6;
        float* cc = out + OFF_CCOORD + (size_t)(b * NGROUP + g) * 3;
        cc[0] = a0; cc[1] = a1; cc[2] = a2;
    }
}

// ---------------------------------------------------------------------------
// distributed top-32 insert (sorted list lives one-slot-per-lane, lanes 0..31)
// comparator is (d2, idx) lexicographic -> insertion order is irrelevant.
// ---------------------------------------------------------------------------
__device__ __forceinline__ void topk_insert(float d2, int p, int lane,
                                            float& ld, int& li, float& kd, int& ki) {
    const bool cand = (d2 < kd) || (d2 == kd && p < ki);
    unsigned long long mask = __ballot(cand);
    while (mask) {
        const int l = __ffsll(mask) - 1;
        mask &= mask - 1;
        const float dc = __shfl(d2, l);
        const int   pc = __shfl(p, l);
        if ((dc < kd) || (dc == kd && pc < ki)) {
            const bool before = (ld < dc) || (ld == dc && li < pc);
            const int pos = (int)__popcll(__ballot(before));
            const float sd = __shfl_up(ld, 1);
            const int   si = __shfl_up(li, 1);
            if (lane == pos)      { ld = dc; li = pc; }
            else if (lane > pos)  { ld = sd; li = si; }
            if (lane >= KNN_K)    { ld = __builtin_inff(); li = 0x7fffffff; }
            kd = __shfl(ld, KNN_K - 1);
            ki = __shfl(li, KNN_K - 1);
        }
    }
}

// ---------------------------------------------------------------------------
// Kernel 2: 32-NN via LDS-staged tiles. 512 threads = 8 waves per block;
// block handles 16 groups (wave w -> groups w and w+8), so each staged tile
// is reused by 16 group-scans. Tile = 1024 points x (7 attrs + x2) SoA
// = 32 KB. Each lane reads 4 consecutive points per array via b128
// (contiguous 16 B/lane -> conflict-free).
// ---------------------------------------------------------------------------
__global__ __launch_bounds__(512) void knn_lds_kernel(const float* __restrict__ xyz,
                                                      const float* __restrict__ x2,
                                                      const float* __restrict__ xt,
                                                      float* __restrict__ out) {
#pragma clang fp contract(off)
    const int lane = threadIdx.x & 63;
    const int w = threadIdx.x >> 6;               // wave 0..7
    const int g0 = blockIdx.x * 16 + w;           // groups g0 and g0+8
    const int b  = (blockIdx.x * 16) >> 10;
    const float* X = xyz + (size_t)b * N_PTS * ATTR;

    __shared__ float Ts[8][1024];                 // T0..T6, XB — 32 KB

    float c[2][7], csq[2], ld[2], kd[2];
    int li[2], ki[2];
#pragma unroll
    for (int g = 0; g < 2; ++g) {
        const int gg = g0 + g * 8;
        const float* C = out + OFF_CATTR + (size_t)gg * ATTR;
#pragma unroll
        for (int a = 0; a < ATTR; ++a) c[g][a] = C[a];
        float s = c[g][0] * c[g][0];
        s = s + c[g][1] * c[g][1];
        s = s + c[g][2] * c[g][2];
        s = s + c[g][3] * c[g][3];
        s = s + c[g][4] * c[g][4];
        s = s + c[g][5] * c[g][5];
        s = s + c[g][6] * c[g][6];
        csq[g] = s;
        ld[g] = __builtin_inff(); li[g] = 0x7fffffff;
        kd[g] = __builtin_inff(); ki[g] = 0x7fffffff;
    }

    for (int tile = 0; tile < N_PTS / 1024; ++tile) {
        // stage: wave w loads array w (w<7: attr w from xt; w==7: x2)
        {
            const float* src = (w < ATTR)
                ? (xt + ((size_t)b * ATTR + w) * N_PTS + tile * 1024)
                : (x2 + (size_t)b * N_PTS + tile * 1024);
            const float4* s4 = (const float4*)src;
            float4* dst = (float4*)Ts[w];
#pragma unroll
            for (int j = 0; j < 4; ++j) dst[j * 64 + lane] = s4[j * 64 + lane];
        }
        __syncthreads();

        for (int it = 0; it < 4; ++it) {
            const int lbase = it * 256 + lane * 4;          // LDS float index
            const int pbase = tile * 1024 + lbase;          // global point index
            float vq[8][4];
#pragma unroll
            for (int a = 0; a < 8; ++a) {
                float4 tv = *(const float4*)&Ts[a][lbase];  // ds_read_b128
                vq[a][0] = tv.x; vq[a][1] = tv.y; vq[a][2] = tv.z; vq[a][3] = tv.w;
            }
#pragma unroll
            for (int g = 0; g < 2; ++g) {
                float d2r[4];
                bool anyc = false;
#pragma unroll
                for (int r = 0; r < 4; ++r) {
                    float dot = c[g][0] * vq[0][r];
                    dot = dot + c[g][1] * vq[1][r];
                    dot = dot + c[g][2] * vq[2][r];
                    dot = dot + c[g][3] * vq[3][r];
                    dot = dot + c[g][4] * vq[4][r];
                    dot = dot + c[g][5] * vq[5][r];
                    dot = dot + c[g][6] * vq[6][r];
                    d2r[r] = (csq[g] + vq[7][r]) - 2.0f * dot;
                    const int p = pbase + r;
                    anyc = anyc || (d2r[r] < kd[g]) || (d2r[r] == kd[g] && p < ki[g]);
                }
                if (__ballot(anyc)) {
#pragma unroll
                    for (int r = 0; r < 4; ++r)
                        topk_insert(d2r[r], pbase + r, lane, ld[g], li[g], kd[g], ki[g]);
                }
            }
        }
        __syncthreads();
    }

    // neighborhood output: lane j writes rank-j neighbor (ascending (d2,idx))
#pragma unroll
    for (int g = 0; g < 2; ++g) {
        if (lane < KNN_K) {
            const int gg = g0 + g * 8;
            const float* q = X + (size_t)li[g] * ATTR;
            float* o = out + OFF_NB + ((size_t)gg * KNN_K + lane) * ATTR;
            o[0] = q[0] - c[g][0];
            o[1] = q[1] - c[g][1];
            o[2] = q[2] - c[g][2];
            o[3] = q[3];
            o[4] = q[4];
            o[5] = q[5];
            o[6] = q[6];
        }
    }
}

// ---------------------------------------------------------------------------
// Fallback (no workspace): one wave per group, AoS direct reads.
// ---------------------------------------------------------------------------
__global__ __launch_bounds__(256) void knn_fallback(const float* __restrict__ xyz,
                                                    float* __restrict__ out) {
#pragma clang fp contract(off)
    const int lane = threadIdx.x & 63;
    const int gg = blockIdx.x * 4 + (threadIdx.x >> 6);
    const int b  = gg >> 10;
    const float* X = xyz + (size_t)b * N_PTS * ATTR;
    const float* C = out + OFF_CATTR + (size_t)gg * ATTR;
    const float c0 = C[0], c1 = C[1], c2a = C[2], c3 = C[3], c4 = C[4], c5 = C[5], c6 = C[6];
    float csq = c0 * c0;
    csq = csq + c1 * c1;
    csq = csq + c2a * c2a;
    csq = csq + c3 * c3;
    csq = csq + c4 * c4;
    csq = csq + c5 * c5;
    csq = csq + c6 * c6;
    float ld = __builtin_inff(); int li = 0x7fffffff;
    float kd = __builtin_inff(); int ki = 0x7fffffff;
    for (int p0 = 0; p0 < N_PTS; p0 += 64) {
        const int p = p0 + lane;
        const float* q = X + (size_t)p * ATTR;
        float dot = c0 * q[0];
        dot = dot + c1 * q[1];
        dot = dot + c2a * q[2];
        dot = dot + c3 * q[3];
        dot = dot + c4 * q[4];
        dot = dot + c5 * q[5];
        dot = dot + c6 * q[6];
        float xx = q[0] * q[0];
        xx = xx + q[1] * q[1];
        xx = xx + q[2] * q[2];
        xx = xx + q[3] * q[3];
        xx = xx + q[4] * q[4];
        xx = xx + q[5] * q[5];
        xx = xx + q[6] * q[6];
        const float d2 = (csq + xx) - 2.0f * dot;
        topk_insert(d2, p, lane, ld, li, kd, ki);
    }
    if (lane < KNN_K) {
        const float* q = X + (size_t)li * ATTR;
        float* o = out + OFF_NB + ((size_t)gg * KNN_K + lane) * ATTR;
        o[0] = q[0] - c0;
        o[1] = q[1] - c1;
        o[2] = q[2] - c2a;
        o[3] = q[3];
        o[4] = q[4];
        o[5] = q[5];
        o[6] = q[6];
    }
}

extern "C" void kernel_launch(void* const* d_in, const int* in_sizes, int n_in,
                              void* d_out, int out_size, void* d_ws, size_t ws_size,
                              hipStream_t stream) {
    const float* xyz = (const float*)d_in[0];
    float* out = (float*)d_out;

    const size_t need = (size_t)(B_SZ * N_PTS) * (1 + ATTR) * sizeof(float);  // 4 MiB
    const bool use_ws = ws_size >= need;
    float* x2 = use_ws ? (float*)d_ws : nullptr;
    float* xt = use_ws ? ((float*)d_ws + B_SZ * N_PTS) : nullptr;

    if (use_ws) {
        prep_kernel<<<(B_SZ * N_PTS + 255) / 256, 256, 0, stream>>>(xyz, x2, xt);
    }
    fps_kernel<<<B_SZ, 1024, 0, stream>>>(xyz, out);
    if (use_ws) {
        knn_lds_kernel<<<(B_SZ * NGROUP) / 16, 512, 0, stream>>>(xyz, x2, xt, out);
    } else {
        knn_fallback<<<(B_SZ * NGROUP) / 4, 256, 0, stream>>>(xyz, out);
    }
}

// Round 5
// 2299.016 us; speedup vs baseline: 1.0850x; 1.0850x over previous
//
#include <hip/hip_runtime.h>

#define N_PTS  16384
#define B_SZ   8
#define NGROUP 1024
#define KNN_K  32
#define ATTR   7

// d_out layout (floats), reference return order:
// neighborhood (8,1024,32,7), center_idx (8,1024), centroids_attrs (8,1024,7), centroids_coors (8,1024,3)
#define OFF_NB     0
#define OFF_IDX    (B_SZ * NGROUP * KNN_K * ATTR)            // 1835008
#define OFF_CATTR  (OFF_IDX + B_SZ * NGROUP)                 // 1843200
#define OFF_CCOORD (OFF_CATTR + B_SZ * NGROUP * ATTR)        // 1900544

typedef float f2u __attribute__((ext_vector_type(2), aligned(4)));     // 4B-aligned vec load

// ---------------------------------------------------------------------------
// Kernel 0: prep — x2[b][n] = sum_a xyz[b][n][a]^2 (sequential, no FMA) and
// SoA transpose xt[b][a][n] for coalesced KNN staging.
// ---------------------------------------------------------------------------
__global__ void prep_kernel(const float* __restrict__ xyz, float* __restrict__ x2,
                            float* __restrict__ xt) {
#pragma clang fp contract(off)
    int i = blockIdx.x * blockDim.x + threadIdx.x;
    if (i >= B_SZ * N_PTS) return;
    const int b = i >> 14;
    const int p = i & (N_PTS - 1);
    const float* q = xyz + (size_t)i * ATTR;
    f2u a01 = *(const f2u*)q;
    f2u a23 = *(const f2u*)(q + 2);
    f2u a45 = *(const f2u*)(q + 4);
    float a6 = q[6];
    float s = a01.x * a01.x;
    s = s + a01.y * a01.y;
    s = s + a23.x * a23.x;
    s = s + a23.y * a23.y;
    s = s + a45.x * a45.x;
    s = s + a45.y * a45.y;
    s = s + a6 * a6;
    x2[i] = s;
    float* T = xt + (size_t)b * ATTR * N_PTS + p;
    T[0 * N_PTS] = a01.x;
    T[1 * N_PTS] = a01.y;
    T[2 * N_PTS] = a23.x;
    T[3 * N_PTS] = a23.y;
    T[4 * N_PTS] = a45.x;
    T[5 * N_PTS] = a45.y;
    T[6 * N_PTS] = a6;
}

// ---------------------------------------------------------------------------
// Kernel 1: farthest point sampling. One 1024-thread block per batch,
// 16 points/thread (strided p = t + j*1024) as plain named scalars.
// amdgpu_waves_per_eu(4,4): pins EXACTLY 4 waves/EU (1 block/CU) so the
// allocator's budget is 128 VGPR/wave and the 64-float state stays in
// architectural VGPRs (R2-R4 kept it in AGPRs at 40-48 VGPR; R3/R4's
// inline-asm "v" constraints added accvgpr copy tax -> regression).
// Per step: distance min-update + value-only running max; f32 wave
// butterfly max; exec-masked owner scan resolves min index; monotone u64
// key (d-bits<<32 | 16384-idx) atomicMax into triple-buffered LDS slot;
// ONE barrier; uniform scalar re-fetch of winner coords from global (L2).
// ---------------------------------------------------------------------------
__global__ __launch_bounds__(1024) __attribute__((amdgpu_waves_per_eu(4, 4)))
void fps_kernel(const float* __restrict__ xyz, float* __restrict__ out) {
#pragma clang fp contract(off)
    const int b = blockIdx.x;
    const int t = threadIdx.x;
    const int lane = t & 63;
    const float* X = xyz + (size_t)b * N_PTS * ATTR;

    float px[16], py[16], pz[16], pd[16];
#pragma unroll
    for (int j = 0; j < 16; ++j) {
        const int p = t + (j << 10);
        const float* q = X + (size_t)p * ATTR;
        f2u u = *(const f2u*)q;
        px[j] = u.x; py[j] = u.y; pz[j] = q[2];
        pd[j] = 1e10f;
    }

    __shared__ unsigned long long slot[3];
    __shared__ int sel[NGROUP];
    if (t == 0) { slot[0] = 0ull; sel[0] = 0; }
    float cx = X[0], cy = X[1], cz = X[2];        // farthest=0 initial centroid
    __syncthreads();

    for (int s = 0; s < NGROUP - 1; ++s) {
        // distance update + value-only running max (2 chains for ILP).
        float m0 = -1.0f, m1 = -1.0f;
#pragma unroll
        for (int j = 0; j < 16; j += 2) {
            {
                float dx = px[j] - cx;
                float dy = py[j] - cy;
                float dz = pz[j] - cz;
                float a  = dx * dx + dy * dy;     // (dx^2+dy^2) — unfused
                a = a + dz * dz;                  // + dz^2 — sequential
                float nd = fminf(pd[j], a);
                pd[j] = nd;
                m0 = fmaxf(m0, nd);
            }
            {
                float dx = px[j + 1] - cx;
                float dy = py[j + 1] - cy;
                float dz = pz[j + 1] - cz;
                float a  = dx * dx + dy * dy;
                a = a + dz * dz;
                float nd = fminf(pd[j + 1], a);
                pd[j + 1] = nd;
                m1 = fmaxf(m1, nd);
            }
        }
        const float tmax = fmaxf(m0, m1);
        // f32 wave-max butterfly
        float wmax = tmax;
#pragma unroll
        for (int off = 1; off < 64; off <<= 1)
            wmax = fmaxf(wmax, __shfl_xor(wmax, off));
        // owner lanes resolve their smallest matching point index
        // (p = t + j*1024: within a thread, lowest j == lowest p)
        int myp = 0x7fffffff;
        if (tmax == wmax) {
#pragma unroll
            for (int j = 15; j >= 0; --j)         // descending: final = lowest p
                if (pd[j] == wmax) myp = t + (j << 10);
        }
        unsigned long long m = __ballot(tmax == wmax);
        int wp = __shfl(myp, __ffsll(m) - 1);
        if (__popcll(m) > 1) {                    // exact-tie path (rare), exact min-p
            unsigned long long mm = m;
            while (mm) {
                int l = __ffsll(mm) - 1; mm &= mm - 1;
                int pp = __shfl(myp, l);
                wp = min(wp, pp);
            }
        }
        // monotone key: larger d wins; tie -> smaller index. d >= 0 so float
        // bits are order-preserving as u32.
        if (lane == 0)
            atomicMax(&slot[s % 3],
                      ((unsigned long long)__float_as_uint(wmax) << 32) |
                      (unsigned)(N_PTS - wp));
        if (t == 0) slot[(s + 1) % 3] = 0ull;     // barrier-ordered reset
        __syncthreads();
        const unsigned long long key = slot[s % 3];
        int bidx = N_PTS - (int)(unsigned)key;
        bidx = __builtin_amdgcn_readfirstlane(bidx);
        if (t == 0) sel[s + 1] = bidx;
        // uniform (SGPR) address -> scalar load of winner coords, L2-hit.
        const float* q = X + (size_t)bidx * ATTR;
        cx = q[0]; cy = q[1]; cz = q[2];
    }
    __syncthreads();

    // outputs: center_idx, centroids_attrs, centroids_coors (1024 threads = 1024 groups)
    {
        const int g = t;
        const int idx = sel[g];
        const float* q = X + (size_t)idx * ATTR;
        float a0 = q[0], a1 = q[1], a2 = q[2], a3 = q[3], a4 = q[4], a5 = q[5], a6 = q[6];
        out[OFF_IDX + b * NGROUP + g] = (float)idx;
        float* ca = out + OFF_CATTR + (size_t)(b * NGROUP + g) * ATTR;
        ca[0] = a0; ca[1] = a1; ca[2] = a2; ca[3] = a3; ca[4] = a4; ca[5] = a5; ca[6] = a6;
        float* cc = out + OFF_CCOORD + (size_t)(b * NGROUP + g) * 3;
        cc[0] = a0; cc[1] = a1; cc[2] = a2;
    }
}

// ---------------------------------------------------------------------------
// distributed top-32 insert (sorted list lives one-slot-per-lane, lanes 0..31)
// comparator is (d2, idx) lexicographic -> insertion order is irrelevant.
// ---------------------------------------------------------------------------
__device__ __forceinline__ void topk_insert(float d2, int p, int lane,
                                            float& ld, int& li, float& kd, int& ki) {
    const bool cand = (d2 < kd) || (d2 == kd && p < ki);
    unsigned long long mask = __ballot(cand);
    while (mask) {
        const int l = __ffsll(mask) - 1;
        mask &= mask - 1;
        const float dc = __shfl(d2, l);
        const int   pc = __shfl(p, l);
        if ((dc < kd) || (dc == kd && pc < ki)) {
            const bool before = (ld < dc) || (ld == dc && li < pc);
            const int pos = (int)__popcll(__ballot(before));
            const float sd = __shfl_up(ld, 1);
            const int   si = __shfl_up(li, 1);
            if (lane == pos)      { ld = dc; li = pc; }
            else if (lane > pos)  { ld = sd; li = si; }
            if (lane >= KNN_K)    { ld = __builtin_inff(); li = 0x7fffffff; }
            kd = __shfl(ld, KNN_K - 1);
            ki = __shfl(li, KNN_K - 1);
        }
    }
}

// ---------------------------------------------------------------------------
// Kernel 2: 32-NN via LDS-staged tiles. 512 threads = 8 waves per block;
// block handles 16 groups (wave w -> groups w and w+8). Tile = 1024 points
// x (7 attrs + x2) SoA = 32 KB. b128 LDS reads, conflict-free.
// ---------------------------------------------------------------------------
__global__ __launch_bounds__(512) void knn_lds_kernel(const float* __restrict__ xyz,
                                                      const float* __restrict__ x2,
                                                      const float* __restrict__ xt,
                                                      float* __restrict__ out) {
#pragma clang fp contract(off)
    const int lane = threadIdx.x & 63;
    const int w = threadIdx.x >> 6;               // wave 0..7
    const int g0 = blockIdx.x * 16 + w;           // groups g0 and g0+8
    const int b  = (blockIdx.x * 16) >> 10;
    const float* X = xyz + (size_t)b * N_PTS * ATTR;

    __shared__ float Ts[8][1024];                 // T0..T6, XB — 32 KB

    float c[2][7], csq[2], ld[2], kd[2];
    int li[2], ki[2];
#pragma unroll
    for (int g = 0; g < 2; ++g) {
        const int gg = g0 + g * 8;
        const float* C = out + OFF_CATTR + (size_t)gg * ATTR;
#pragma unroll
        for (int a = 0; a < ATTR; ++a) c[g][a] = C[a];
        float s = c[g][0] * c[g][0];
        s = s + c[g][1] * c[g][1];
        s = s + c[g][2] * c[g][2];
        s = s + c[g][3] * c[g][3];
        s = s + c[g][4] * c[g][4];
        s = s + c[g][5] * c[g][5];
        s = s + c[g][6] * c[g][6];
        csq[g] = s;
        ld[g] = __builtin_inff(); li[g] = 0x7fffffff;
        kd[g] = __builtin_inff(); ki[g] = 0x7fffffff;
    }

    for (int tile = 0; tile < N_PTS / 1024; ++tile) {
        // stage: wave w loads array w (w<7: attr w from xt; w==7: x2)
        {
            const float* src = (w < ATTR)
                ? (xt + ((size_t)b * ATTR + w) * N_PTS + tile * 1024)
                : (x2 + (size_t)b * N_PTS + tile * 1024);
            const float4* s4 = (const float4*)src;
            float4* dst = (float4*)Ts[w];
#pragma unroll
            for (int j = 0; j < 4; ++j) dst[j * 64 + lane] = s4[j * 64 + lane];
        }
        __syncthreads();

        for (int it = 0; it < 4; ++it) {
            const int lbase = it * 256 + lane * 4;          // LDS float index
            const int pbase = tile * 1024 + lbase;          // global point index
            float vq[8][4];
#pragma unroll
            for (int a = 0; a < 8; ++a) {
                float4 tv = *(const float4*)&Ts[a][lbase];  // ds_read_b128
                vq[a][0] = tv.x; vq[a][1] = tv.y; vq[a][2] = tv.z; vq[a][3] = tv.w;
            }
#pragma unroll
            for (int g = 0; g < 2; ++g) {
                float d2r[4];
                bool anyc = false;
#pragma unroll
                for (int r = 0; r < 4; ++r) {
                    float dot = c[g][0] * vq[0][r];
                    dot = dot + c[g][1] * vq[1][r];
                    dot = dot + c[g][2] * vq[2][r];
                    dot = dot + c[g][3] * vq[3][r];
                    dot = dot + c[g][4] * vq[4][r];
                    dot = dot + c[g][5] * vq[5][r];
                    dot = dot + c[g][6] * vq[6][r];
                    d2r[r] = (csq[g] + vq[7][r]) - 2.0f * dot;
                    const int p = pbase + r;
                    anyc = anyc || (d2r[r] < kd[g]) || (d2r[r] == kd[g] && p < ki[g]);
                }
                if (__ballot(anyc)) {
#pragma unroll
                    for (int r = 0; r < 4; ++r)
                        topk_insert(d2r[r], pbase + r, lane, ld[g], li[g], kd[g], ki[g]);
                }
            }
        }
        __syncthreads();
    }

    // neighborhood output: lane j writes rank-j neighbor (ascending (d2,idx))
#pragma unroll
    for (int g = 0; g < 2; ++g) {
        if (lane < KNN_K) {
            const int gg = g0 + g * 8;
            const float* q = X + (size_t)li[g] * ATTR;
            float* o = out + OFF_NB + ((size_t)gg * KNN_K + lane) * ATTR;
            o[0] = q[0] - c[g][0];
            o[1] = q[1] - c[g][1];
            o[2] = q[2] - c[g][2];
            o[3] = q[3];
            o[4] = q[4];
            o[5] = q[5];
            o[6] = q[6];
        }
    }
}

// ---------------------------------------------------------------------------
// Fallback (no workspace): one wave per group, AoS direct reads.
// ---------------------------------------------------------------------------
__global__ __launch_bounds__(256) void knn_fallback(const float* __restrict__ xyz,
                                                    float* __restrict__ out) {
#pragma clang fp contract(off)
    const int lane = threadIdx.x & 63;
    const int gg = blockIdx.x * 4 + (threadIdx.x >> 6);
    const int b  = gg >> 10;
    const float* X = xyz + (size_t)b * N_PTS * ATTR;
    const float* C = out + OFF_CATTR + (size_t)gg * ATTR;
    const float c0 = C[0], c1 = C[1], c2a = C[2], c3 = C[3], c4 = C[4], c5 = C[5], c6 = C[6];
    float csq = c0 * c0;
    csq = csq + c1 * c1;
    csq = csq + c2a * c2a;
    csq = csq + c3 * c3;
    csq = csq + c4 * c4;
    csq = csq + c5 * c5;
    csq = csq + c6 * c6;
    float ld = __builtin_inff(); int li = 0x7fffffff;
    float kd = __builtin_inff(); int ki = 0x7fffffff;
    for (int p0 = 0; p0 < N_PTS; p0 += 64) {
        const int p = p0 + lane;
        const float* q = X + (size_t)p * ATTR;
        float dot = c0 * q[0];
        dot = dot + c1 * q[1];
        dot = dot + c2a * q[2];
        dot = dot + c3 * q[3];
        dot = dot + c4 * q[4];
        dot = dot + c5 * q[5];
        dot = dot + c6 * q[6];
        float xx = q[0] * q[0];
        xx = xx + q[1] * q[1];
        xx = xx + q[2] * q[2];
        xx = xx + q[3] * q[3];
        xx = xx + q[4] * q[4];
        xx = xx + q[5] * q[5];
        xx = xx + q[6] * q[6];
        const float d2 = (csq + xx) - 2.0f * dot;
        topk_insert(d2, p, lane, ld, li, kd, ki);
    }
    if (lane < KNN_K) {
        const float* q = X + (size_t)li * ATTR;
        float* o = out + OFF_NB + ((size_t)gg * KNN_K + lane) * ATTR;
        o[0] = q[0] - c0;
        o[1] = q[1] - c1;
        o[2] = q[2] - c2a;
        o[3] = q[3];
        o[4] = q[4];
        o[5] = q[5];
        o[6] = q[6];
    }
}

extern "C" void kernel_launch(void* const* d_in, const int* in_sizes, int n_in,
                              void* d_out, int out_size, void* d_ws, size_t ws_size,
                              hipStream_t stream) {
    const float* xyz = (const float*)d_in[0];
    float* out = (float*)d_out;

    const size_t need = (size_t)(B_SZ * N_PTS) * (1 + ATTR) * sizeof(float);  // 4 MiB
    const bool use_ws = ws_size >= need;
    float* x2 = use_ws ? (float*)d_ws : nullptr;
    float* xt = use_ws ? ((float*)d_ws + B_SZ * N_PTS) : nullptr;

    if (use_ws) {
        prep_kernel<<<(B_SZ * N_PTS + 255) / 256, 256, 0, stream>>>(xyz, x2, xt);
    }
    fps_kernel<<<B_SZ, 1024, 0, stream>>>(xyz, out);
    if (use_ws) {
        knn_lds_kernel<<<(B_SZ * NGROUP) / 16, 512, 0, stream>>>(xyz, x2, xt, out);
    } else {
        knn_fallback<<<(B_SZ * NGROUP) / 4, 256, 0, stream>>>(xyz, out);
    }
}